// Round 9
// baseline (122.006 us; speedup 1.0000x reference)
//
#include <hip/hip_runtime.h>
#include <math.h>

#define L_TOT 393216
#define L_D4  98304
#define NPORT 32
#define NPEAK 12
#define NOFF  21
#define NCAND 252              // NPEAK * NOFF
#define TILE  1536
#define NBLK  (L_TOT / TILE)   // 256
#define NSLOT 12
#define HALF_ELEMS 12582912ull // 32 * 393216 (real plane in fp32 elems)

// Scratch in module __device__ globals; every word unconditionally rewritten
// each call (stream-ordered: search -> select -> fused).
__device__ float2 g_F[NBLK * NCAND];   // [block][cand]
__device__ double g_npart[NBLK];       // per-block noise partials
// g_prm: [0]=nd | [1+s]=p | [13+s]=T | [25+s]=m | [37+s]=count | [49+s]=portmask
__device__ int    g_prm[96];
__device__ float  g_scale[1];          // 1/(1+noise_power)

__constant__ double c_cos12[12] = {1.0, 0.8660254037844387, 0.5, 0.0, -0.5,
  -0.8660254037844387, -1.0, -0.8660254037844387, -0.5, 0.0, 0.5, 0.8660254037844387};
__constant__ double c_sin12[12] = {0.0, 0.5, 0.8660254037844387, 1.0,
  0.8660254037844387, 0.5, 0.0, -0.5, -0.8660254037844387, -1.0,
  -0.8660254037844387, -0.5};

__device__ __forceinline__ void interp_coords(int n, int* j0, float* f) {
  float x = ((float)n - 1.5f) * 0.25f;          // exact in fp32 (n < 2^19)
  if (x <= 0.f)                    { *j0 = 0;        *f = 0.f; }
  else if (x >= (float)(L_D4 - 1)) { *j0 = L_D4 - 2; *f = 1.f; }
  else { int jj = (int)x; *j0 = jj; *f = x - (float)jj; }
}

// z^T with SCALAR T -> s_cbranch, <=3 cmults.
__device__ __forceinline__ float2 zpowS(float2 z, float2 z2, float2 z4, float2 z8, int T) {
  int t = T < 0 ? -T : T;
  float cr = 1.f, ci = 0.f;
  if (t & 1) { cr = z.x; ci = z.y; }
  if (t & 2) { float a = cr*z2.x - ci*z2.y, b = cr*z2.y + ci*z2.x; cr = a; ci = b; }
  if (t & 4) { float a = cr*z4.x - ci*z4.y, b = cr*z4.y + ci*z4.x; cr = a; ci = b; }
  if (t & 8) { float a = cr*z8.x - ci*z8.y, b = cr*z8.y + ci*z8.x; cr = a; ci = b; }
  if (T < 0) ci = -ci;
  return make_float2(cr, ci);
}

// F[c] partial sums per tile + noise partials. Each sample touched once.
__global__ __launch_bounds__(256) void search_kernel(
    const float* __restrict__ lsr, const float* __restrict__ lsi) {
  __shared__ float2 sh_ls[TILE + 1];
  __shared__ float2 sh_z[TILE];
  __shared__ float2 sh_red[NCAND * NOFF];      // 42.3 KB (reused for noise reduce)
  const float w = (float)(2.0 * M_PI / (double)L_TOT);
  int tid = threadIdx.x;
  int KB = blockIdx.x * TILE;
  for (int i = tid; i < TILE + 1; i += 256) {
    int k = KB + i; if (k > L_TOT - 1) k = L_TOT - 1;
    sh_ls[i] = make_float2(lsr[k], lsi[k]);
  }
  for (int i = tid; i < TILE; i += 256) {
    float s, c; __sincosf(w * (float)(KB + i), &s, &c);
    sh_z[i] = make_float2(c, s);
  }
  __syncthreads();

  if (tid < NCAND) {
    int r = tid % 12, lane = tid / 12;         // lane in [0,21)
    float accr[NOFF], acci[NOFF];
#pragma unroll
    for (int d = 0; d < NOFF; ++d) { accr[d] = 0.f; acci[d] = 0.f; }
    for (int q = lane; q < TILE / 12; q += 21) {
      int kl = 12 * q + r;
      float2 y = sh_ls[kl];
      float2 z = sh_z[kl];
      accr[10] += y.x; acci[10] += y.y;        // delta = 0
      float cpr = y.x, cpi = y.y, cmr = y.x, cmi = y.y;
#pragma unroll
      for (int d = 1; d <= 10; ++d) {
        float tr = cpr*z.x - cpi*z.y, ti = cpr*z.y + cpi*z.x; cpr = tr; cpi = ti;
        accr[10 + d] += cpr; acci[10 + d] += cpi;          // * z^{+d}
        tr = cmr*z.x + cmi*z.y; ti = cmi*z.x - cmr*z.y; cmr = tr; cmi = ti;
        accr[10 - d] += cmr; acci[10 - d] += cmi;          // * z^{-d}
      }
    }
#pragma unroll
    for (int d = 0; d < NOFF; ++d)
      sh_red[tid * NOFF + d] = make_float2(accr[d], acci[d]);
  }
  double nacc = 0.0;
  int top = (KB + TILE <= L_TOT - 1) ? TILE : (L_TOT - 1 - KB);
  for (int i = tid; i < top; i += 256) {
    float2 a = sh_ls[i], b = sh_ls[i + 1];
    float dr = b.x - a.x, di = b.y - a.y;
    nacc += (double)(dr * dr + di * di);
  }
  __syncthreads();
  if (tid < NCAND) {                           // reduce 21 lanes -> F[c], c=tid
    int r = tid / NOFF, dd = tid - r * NOFF;
    float fr = 0.f, fi = 0.f;
    for (int lane = 0; lane < 21; ++lane) {
      float2 v = sh_red[(lane * 12 + r) * NOFF + dd];
      fr += v.x; fi += v.y;
    }
    g_F[blockIdx.x * NCAND + tid] = make_float2(fr, fi);
  }
  __syncthreads();                             // before reusing sh_red
  double* nb = (double*)sh_red;
  nb[tid] = nacc;
  __syncthreads();
  for (int t = 128; t > 0; t >>= 1) {
    if (tid < t) nb[tid] += nb[tid + t];
    __syncthreads();
  }
  if (tid == 0) g_npart[blockIdx.x] = nb[0];
}

// Merged reduce+select+dedupe, 1 block.
__global__ __launch_bounds__(256) void select_kernel(
    const int* __restrict__ shifts) {
  __shared__ double sGr[NCAND], sGi[NCAND];
  __shared__ double hmag[NCAND];
  __shared__ double nred[256];
  __shared__ int    sh_pu[NPORT], sh_Tu[NPORT];
  int tid = threadIdx.x;
  if (tid < NCAND) {
    double gr = 0.0, gi = 0.0;
    for (int b = 0; b < NBLK; ++b) {
      float2 v = g_F[b * NCAND + tid];
      gr += (double)v.x; gi += (double)v.y;
    }
    sGr[tid] = gr; sGi[tid] = gi;
  }
  nred[tid] = g_npart[tid];
  __syncthreads();
  if (tid < NCAND) {
    int p = tid / NOFF, dd = tid - p * NOFF;
    double sr = 0.0, si = 0.0;
    for (int r = 0; r < 12; ++r) {
      int idx = (p * r) % 12;
      double gr = sGr[r * NOFF + dd], gi = sGi[r * NOFF + dd];
      sr += c_cos12[idx] * gr - c_sin12[idx] * gi;
      si += c_cos12[idx] * gi + c_sin12[idx] * gr;
    }
    hmag[tid] = sr * sr + si * si;
  }
  __syncthreads();
  for (int t = 128; t > 0; t >>= 1) {
    if (tid < t) nred[tid] += nred[tid + t];
    __syncthreads();
  }
  if (tid < NPORT) {
    int s = shifts[tid];
    int p = (NPEAK - (s % NPEAK)) % NPEAK;
    double best = -1.0; int bd = 0;
    for (int d = 0; d < NOFF; ++d) {           // first-occurrence argmax
      double v = hmag[p * NOFF + d];
      if (v > best) { best = v; bd = d; }
    }
    sh_pu[tid] = p;
    sh_Tu[tid] = bd - 10;
  }
  __syncthreads();
  if (tid == 0) {
    // dedupe ports by p into slots
    int nd = 0;
    int pv[NSLOT], tv[NSLOT], mv[NSLOT], cv[NSLOT]; unsigned msk[NSLOT];
#pragma unroll
    for (int s = 0; s < NSLOT; ++s) { pv[s] = 0; tv[s] = 0; mv[s] = 0; cv[s] = 0; msk[s] = 0u; }
    for (int u = 0; u < NPORT; ++u) {
      int p = sh_pu[u];
      int slot = -1;
      for (int s = 0; s < nd; ++s) if (pv[s] == p) { slot = s; break; }
      if (slot < 0) {
        slot = nd++;
        pv[slot] = p; tv[slot] = sh_Tu[u];
        int m = sh_Tu[u] + p * (L_TOT / NPEAK);
        if (m < 0) m += L_TOT;
        mv[slot] = m;
      }
      cv[slot] += 1;
      msk[slot] |= (1u << u);
    }
    g_prm[0] = nd;
#pragma unroll
    for (int s = 0; s < NSLOT; ++s) {
      g_prm[1 + s]  = pv[s];
      g_prm[13 + s] = tv[s];
      g_prm[25 + s] = mv[s];
      g_prm[37 + s] = cv[s];
      g_prm[49 + s] = (int)msk[s];
    }
    double npow = nred[0] / (double)(L_TOT - 1) * 0.5;
    g_scale[0] = (float)(1.0 / (1.0 + npow));
  }
}

// One thread per output sample n. Work is per-SLOT (<=12 distinct p), each
// slot's row broadcast to its ports via scalar bitmask loop.
__global__ __launch_bounds__(256) void fused_kernel(
    const float* __restrict__ lsr, const float* __restrict__ lsi,
    float* __restrict__ out, unsigned long long out_elems) {
  __shared__ float2 sh_ls[264];
  __shared__ float2 sh_h[16][67];              // [slot][interp point], padded
  __shared__ float2 sh_tbl[144];
  __shared__ float2 sh_stp1[NSLOT];            // e^{i w m_s}
  __shared__ int    sm_T[NSLOT], sm_p[NSLOT], sm_m[NSLOT], sm_cnt[NSLOT], sm_msk[NSLOT];
  __shared__ int    sm_nd;
  __shared__ float  sm_scale;

  const float w = (float)(2.0 * M_PI / (double)L_TOT);
  int tid = threadIdx.x;
  int N0 = blockIdx.x * 256;
  int JBASE; float fd;
  interp_coords(N0, &JBASE, &fd);              // block-uniform (min j0 in block)
  int K0 = 4 * JBASE;

  if (tid < NSLOT) {
    sm_T[tid] = g_prm[13 + tid];
    sm_p[tid] = g_prm[1 + tid];
    int m = g_prm[25 + tid]; sm_m[tid] = m;
    sm_cnt[tid] = g_prm[37 + tid];
    sm_msk[tid] = g_prm[49 + tid];
    float s, c; __sincosf(w * (float)m, &s, &c);
    sh_stp1[tid] = make_float2(c, s);
  }
  if (tid == 0) { sm_nd = g_prm[0]; sm_scale = g_scale[0]; }
  if (tid < 144) {
    int p = tid / 12, r = tid - p * 12;
    int idx = (p * r) % 12;
    float s, c; __sincosf((float)(2.0 * M_PI / 12.0) * (float)idx, &s, &c);
    sh_tbl[tid] = make_float2(c, s);
  }
  for (int i = tid; i < 264; i += 256) {
    int k = K0 + i; if (k > L_TOT - 1) k = L_TOT - 1;
    sh_ls[i] = make_float2(lsr[k], lsi[k]);
  }
  __syncthreads();

  int nd = __builtin_amdgcn_readfirstlane(sm_nd);

  // havg tile for nd slots: h[s][jj] = 0.25 * sum_{t<4} ls[k]*e^{i w (m k mod L)}
  for (int e = tid; e < 66 * 16; e += 256) {
    int s = e & 15, jj = e >> 4;
    if (s < nd) {
      int j = JBASE + jj; if (j > L_D4 - 1) j = L_D4 - 1;
      int k0 = 4 * j, kk = k0 - K0;
      unsigned rr = (unsigned)(((long long)sm_m[s] * k0) % L_TOT);
      float phs, phc; __sincosf(w * (float)rr, &phs, &phc);
      float2 stp = sh_stp1[s];
      float sr = 0.f, si = 0.f;
#pragma unroll
      for (int t = 0; t < 4; ++t) {
        float2 v = sh_ls[kk + t];
        sr += v.x * phc - v.y * phs;
        si += v.x * phs + v.y * phc;
        float a = phc * stp.x - phs * stp.y, b = phc * stp.y + phs * stp.x;
        phc = a; phs = b;
      }
      sh_h[s][jj] = make_float2(0.25f * sr, 0.25f * si);
    }
  }
  __syncthreads();

  int n = N0 + tid;
  int j0; float f;
  interp_coords(n, &j0, &f);
  int jj0 = j0 - JBASE;                        // in [0, 64]
  int r12 = n % 12;
  float2 lsn = sh_ls[n - K0];
  float zs, zc; __sincosf(w * (float)n, &zs, &zc);
  float2 zn = make_float2(zc, zs);
  float2 z2 = make_float2(zn.x*zn.x - zn.y*zn.y, 2.f*zn.x*zn.y);
  float2 z4 = make_float2(z2.x*z2.x - z2.y*z2.y, 2.f*z2.x*z2.y);
  float2 z8 = make_float2(z4.x*z4.x - z4.y*z4.y, 2.f*z4.x*z4.y);

  // pass 1: per-slot A_s = h_interp*conj(z^T); recon = sum_s cnt_s * A_s*conj(tb_s)
  float aAr[NSLOT], aAi[NSLOT];
  float rcr = 0.f, rci = 0.f;
#pragma unroll
  for (int s = 0; s < NSLOT; ++s) {
    if (s < nd) {
      int T = __builtin_amdgcn_readfirstlane(sm_T[s]);
      int p = __builtin_amdgcn_readfirstlane(sm_p[s]);
      float cnt = (float)__builtin_amdgcn_readfirstlane(sm_cnt[s]);
      float2 zT = zpowS(zn, z2, z4, z8, T);
      float2 tb = sh_tbl[p * 12 + r12];
      float2 y0 = sh_h[s][jj0], y1 = sh_h[s][jj0 + 1];
      float hr = y0.x + f * (y1.x - y0.x);
      float hi = y0.y + f * (y1.y - y0.y);
      float Ar = hr * zT.x + hi * zT.y;        // A = h * conj(zT)
      float Ai = hi * zT.x - hr * zT.y;
      aAr[s] = Ar; aAi[s] = Ai;
      rcr += cnt * (Ar * tb.x + Ai * tb.y);    // recon += cnt * A * conj(tb)
      rci += cnt * (Ai * tb.x - Ar * tb.y);
    } else { aAr[s] = 0.f; aAi[s] = 0.f; }
  }
  float resr = lsn.x - rcr, resi = lsn.y - rci;
  float scl = sm_scale;

  // pass 2: per-slot row, broadcast to ports via scalar bitmask
  bool full = (out_elems >= 2ull * HALF_ELEMS);
#pragma unroll
  for (int s = 0; s < NSLOT; ++s) {
    if (s < nd) {
      int p = __builtin_amdgcn_readfirstlane(sm_p[s]);
      unsigned mask = (unsigned)__builtin_amdgcn_readfirstlane(sm_msk[s]);
      float2 tb = sh_tbl[p * 12 + r12];
      float orr = scl * (aAr[s] + resr * tb.x - resi * tb.y);
      float oii = scl * (aAi[s] + resr * tb.y + resi * tb.x);
      while (mask) {
        int u = __builtin_ctz(mask); mask &= mask - 1;
        unsigned long long o = (unsigned long long)u * L_TOT + (unsigned)n;
        if (full) {
          out[o] = orr;
          out[HALF_ELEMS + o] = oii;
        } else {
          if (o < out_elems)              out[o] = orr;
          if (HALF_ELEMS + o < out_elems) out[HALF_ELEMS + o] = oii;
        }
      }
    }
  }
}

extern "C" void kernel_launch(void* const* d_in, const int* in_sizes, int n_in,
                              void* d_out, int out_size, void* d_ws, size_t ws_size,
                              hipStream_t stream) {
  const float* lsr    = (const float*)d_in[0];
  const float* lsi    = (const float*)d_in[1];
  const int*   shifts = (const int*)d_in[2];
  float* out = (float*)d_out;

  if (in_sizes[0] != L_TOT || in_sizes[1] != L_TOT) return;  // defensive: never fault

  unsigned long long out_elems = (unsigned long long)(out_size > 0 ? out_size : 0);

  search_kernel<<<NBLK, 256, 0, stream>>>(lsr, lsi);
  select_kernel<<<1, 256, 0, stream>>>(shifts);
  fused_kernel<<<L_TOT / 256, 256, 0, stream>>>(lsr, lsi, out, out_elems);
}